// Round 1
// baseline (266.348 us; speedup 1.0000x reference)
//
#include <hip/hip_runtime.h>

#define B_ 8
#define N_ 1024
#define DIM_ 768
#define H_ 12
#define DH_ 64
#define M_ (B_ * N_)       // 8192
#define NQKV_ (3 * DIM_)   // 2304
#define SCL_ 0.18033688011112042f  // (1/sqrt(64)) * log2(e)

typedef unsigned short u16;
typedef __attribute__((ext_vector_type(8))) unsigned short u16x8;
typedef __attribute__((ext_vector_type(4))) unsigned short u16x4;
typedef __attribute__((ext_vector_type(8))) short bf16x8;
typedef __attribute__((ext_vector_type(4))) float f32x4;

__device__ __forceinline__ u16 f2bf(float f) {
  unsigned int u = __builtin_bit_cast(unsigned int, f);
  u += 0x7fffu + ((u >> 16) & 1u);
  return (u16)(u >> 16);
}
__device__ __forceinline__ float bf2f(u16 v) {
  unsigned int u = ((unsigned int)v) << 16;
  return __builtin_bit_cast(float, u);
}
__device__ __forceinline__ void async16(const void* g, void* l) {
  __builtin_amdgcn_global_load_lds(
      (const __attribute__((address_space(1))) unsigned int*)g,
      (__attribute__((address_space(3))) unsigned int*)l, 16, 0, 0);
}

// ---------------- cast fp32 -> bf16, vectorized x4 ----------------
__global__ __launch_bounds__(256) void cast_bf16_k(const float* __restrict__ in,
                                                   u16* __restrict__ out, int n4) {
  int i = blockIdx.x * 256 + threadIdx.x;
  if (i >= n4) return;
  float4 v = reinterpret_cast<const float4*>(in)[i];
  u16x4 o;
  o.x = f2bf(v.x); o.y = f2bf(v.y); o.z = f2bf(v.z); o.w = f2bf(v.w);
  reinterpret_cast<u16x4*>(out)[i] = o;
}

// ---------------- C = A * B^T  (A:[M,K], B:[N,K], both bf16 row-major) -----
// m97 structure: 128x128 tile, BK=32, 4 waves (2x2), 4x4 16x16x32 MFMA frags.
// LDS staged via global_load_lds(16B) with SOURCE-side slot swizzle
// (slot ^= row&3) so fragment ds_read_b128 is only 4-way conflicted.
template <bool OUT_BF16, bool BIAS>
__global__ __launch_bounds__(256) void gemm_bt_k(
    const u16* __restrict__ A, const u16* __restrict__ Bm,
    void* __restrict__ Cv, const float* __restrict__ bias, int K, int ldc) {
  __shared__ u16 As[128 * 32];
  __shared__ u16 Bs[128 * 32];
  const int t = threadIdx.x;
  const int lane = t & 63;
  const int wid = t >> 6;
  const int brow = blockIdx.y << 7;
  const int bcol = blockIdx.x << 7;
  const int wrow = (wid >> 1) << 6;
  const int wcol = (wid & 1) << 6;

  f32x4 acc[4][4];
#pragma unroll
  for (int m = 0; m < 4; ++m)
#pragma unroll
    for (int n = 0; n < 4; ++n) acc[m][n] = (f32x4){0.f, 0.f, 0.f, 0.f};

  // staging geometry: thread t stages 16B chunks at linear LDS bytes
  // loff = (t + c*256)*16; row r = loff>>6; physical slot = (loff>>4)&3;
  // global source uses logical slot = phys ^ (r&3)  (involution).
  const int loff0 = t << 4, loff1 = (t + 256) << 4;
  const int r0 = loff0 >> 6, r1 = loff1 >> 6;
  const int s0 = ((((loff0 >> 4) & 3) ^ (r0 & 3)) << 3);
  const int s1 = ((((loff1 >> 4) & 3) ^ (r1 & 3)) << 3);
  const u16* gA0 = A + (size_t)(brow + r0) * K + s0;
  const u16* gA1 = A + (size_t)(brow + r1) * K + s1;
  const u16* gB0 = Bm + (size_t)(bcol + r0) * K + s0;
  const u16* gB1 = Bm + (size_t)(bcol + r1) * K + s1;
  char* lA = (char*)As;
  char* lB = (char*)Bs;

  // fragment read byte-offsets (swizzled)
  const int kb = (lane >> 4) << 4;
  int aoff[4], boff[4];
#pragma unroll
  for (int m = 0; m < 4; ++m) {
    int ra = wrow + (m << 4) + (lane & 15);
    aoff[m] = (ra << 6) + (kb ^ ((ra & 3) << 4));
    int rb = wcol + (m << 4) + (lane & 15);
    boff[m] = (rb << 6) + (kb ^ ((rb & 3) << 4));
  }

  const int nkt = K >> 5;
  for (int kt = 0; kt < nkt; ++kt) {
    const int ko = kt << 5;
    async16(gA0 + ko, lA + loff0);
    async16(gA1 + ko, lA + loff1);
    async16(gB0 + ko, lB + loff0);
    async16(gB1 + ko, lB + loff1);
    __syncthreads();  // drains vmcnt(0) -> staging complete
    bf16x8 af[4], bfr[4];
#pragma unroll
    for (int m = 0; m < 4; ++m) af[m] = *(const bf16x8*)(lA + aoff[m]);
#pragma unroll
    for (int n = 0; n < 4; ++n) bfr[n] = *(const bf16x8*)(lB + boff[n]);
#pragma unroll
    for (int m = 0; m < 4; ++m)
#pragma unroll
      for (int n = 0; n < 4; ++n)
        acc[m][n] = __builtin_amdgcn_mfma_f32_16x16x32_bf16(af[m], bfr[n],
                                                            acc[m][n], 0, 0, 0);
    __syncthreads();  // protect LDS from next iteration's staging
  }

  // epilogue: C/D layout col=lane&15, row=(lane>>4)*4+j  [m89/m91]
  const int crow = brow + wrow + ((lane >> 4) << 2);
  const int ccol0 = bcol + wcol + (lane & 15);
#pragma unroll
  for (int m = 0; m < 4; ++m)
#pragma unroll
    for (int n = 0; n < 4; ++n) {
      int col = ccol0 + (n << 4);
      float bv = BIAS ? bias[col] : 0.f;
#pragma unroll
      for (int j = 0; j < 4; ++j) {
        int row = crow + (m << 4) + j;
        if (OUT_BF16)
          ((u16*)Cv)[(size_t)row * ldc + col] = f2bf(acc[m][n][j]);
        else
          ((float*)Cv)[(size_t)row * ldc + col] = acc[m][n][j] + bv;
      }
    }
}

// ---------------- fused flash attention ----------------
// block = 4 waves, 64 Q rows (16/wave); loop over 16 KV tiles of 64.
// Q pre-scaled by SCALE*log2e, softmax in exp2 domain.
__global__ __launch_bounds__(256) void attn_k(const u16* __restrict__ qkv,
                                              u16* __restrict__ ob) {
  __shared__ u16 Ks[64 * 64];      // [kv][d], XOR-swizzled rows (128B stride)
  __shared__ u16 Vt[64 * 64];      // [d][kv], XOR-swizzled
  __shared__ u16 Ps[4][16 * 64];   // per-wave P [q][kv], XOR-swizzled
  const int t = threadIdx.x;
  const int lane = t & 63;
  const int w = t >> 6;
  const int qt = blockIdx.x & 15;
  const int hb = blockIdx.x >> 4;  // b*12 + h ; adjacent blocks share a head's K/V
  const int b = hb / H_;
  const int h = hb - b * H_;
  const int rowbase = b * N_;
  const int qcol = h * DH_;
  const int kcol = DIM_ + qcol;
  const int vcol = 2 * DIM_ + qcol;

  // Q fragments (A-operand: row=lane&15, k=(lane>>4)*8+j), scaled
  bf16x8 qf[2];
  {
    const int qrow = rowbase + (qt << 6) + (w << 4) + (lane & 15);
    const u16* src = qkv + (size_t)qrow * NQKV_ + qcol + ((lane >> 4) << 3);
#pragma unroll
    for (int ks = 0; ks < 2; ++ks) {
      u16x8 raw = *(const u16x8*)(src + ks * 32);
      bf16x8 o;
#pragma unroll
      for (int j = 0; j < 8; ++j) o[j] = (short)f2bf(bf2f(raw[j]) * SCL_);
      qf[ks] = o;
    }
  }

  float mrow[4], lrow[4];
  f32x4 oacc[4];
#pragma unroll
  for (int j = 0; j < 4; ++j) { mrow[j] = -1e30f; lrow[j] = 0.f; }
#pragma unroll
  for (int d = 0; d < 4; ++d) oacc[d] = (f32x4){0.f, 0.f, 0.f, 0.f};

  const int sr = t >> 2;         // staging row 0..63
  const int sc = (t & 3) << 4;   // staging col start (16 elems)
  const u16* kbase = qkv + (size_t)rowbase * NQKV_ + kcol;
  const u16* vbase = qkv + (size_t)rowbase * NQKV_ + vcol;

  for (int kv = 0; kv < 16; ++kv) {
    __syncthreads();  // previous tile's LDS reads done before restaging
    {
      const u16* kg = kbase + (size_t)(kv * 64 + sr) * NQKV_ + sc;
#pragma unroll
      for (int c = 0; c < 2; ++c) {
        int bo = (sc + c * 8) * 2;
        *(bf16x8*)((char*)Ks + sr * 128 + (bo ^ ((sr & 7) << 4))) =
            *(const bf16x8*)(kg + c * 8);
      }
      const u16* vg = vbase + (size_t)(kv * 64 + sr) * NQKV_ + sc;
      u16 vv[16];
      *(u16x8*)(vv) = *(const u16x8*)(vg);
      *(u16x8*)(vv + 8) = *(const u16x8*)(vg + 8);
#pragma unroll
      for (int j = 0; j < 16; ++j) {  // transpose: Vt[d][kv]
        int d = sc + j;
        *(u16*)((char*)Vt + d * 128 + ((sr * 2) ^ ((d & 7) << 4))) = vv[j];
      }
    }
    __syncthreads();

    // S = Q K^T : 4 kv-col tiles x 2 k-steps
    f32x4 s[4];
#pragma unroll
    for (int n = 0; n < 4; ++n) s[n] = (f32x4){0.f, 0.f, 0.f, 0.f};
#pragma unroll
    for (int n = 0; n < 4; ++n) {
      int rk = (n << 4) + (lane & 15);
#pragma unroll
      for (int ks = 0; ks < 2; ++ks) {
        int off = (rk << 7) +
                  ((((ks << 6) + ((lane >> 4) << 4))) ^ ((rk & 7) << 4));
        bf16x8 kf = *(const bf16x8*)((const char*)Ks + off);
        s[n] = __builtin_amdgcn_mfma_f32_16x16x32_bf16(qf[ks], kf, s[n], 0, 0, 0);
      }
    }

    // online softmax (rows live in 16-lane groups; reg j = row (lane>>4)*4+j)
    float mx[4];
#pragma unroll
    for (int j = 0; j < 4; ++j)
      mx[j] = fmaxf(fmaxf(s[0][j], s[1][j]), fmaxf(s[2][j], s[3][j]));
#pragma unroll
    for (int off = 1; off < 16; off <<= 1)
#pragma unroll
      for (int j = 0; j < 4; ++j)
        mx[j] = fmaxf(mx[j], __shfl_xor(mx[j], off, 64));

    float al[4], ps[4];
    u16 pb[4][4];
#pragma unroll
    for (int j = 0; j < 4; ++j) {
      float mn = fmaxf(mrow[j], mx[j]);
      al[j] = exp2f(mrow[j] - mn);
      mrow[j] = mn;
      ps[j] = 0.f;
    }
#pragma unroll
    for (int n = 0; n < 4; ++n)
#pragma unroll
      for (int j = 0; j < 4; ++j) {
        float p = exp2f(s[n][j] - mrow[j]);
        ps[j] += p;
        pb[n][j] = f2bf(p);
      }
#pragma unroll
    for (int off = 1; off < 16; off <<= 1)
#pragma unroll
      for (int j = 0; j < 4; ++j) ps[j] += __shfl_xor(ps[j], off, 64);
#pragma unroll
    for (int j = 0; j < 4; ++j) lrow[j] = lrow[j] * al[j] + ps[j];
#pragma unroll
    for (int d = 0; d < 4; ++d)
#pragma unroll
      for (int j = 0; j < 4; ++j) oacc[d][j] *= al[j];

    // P (C-layout) -> per-wave LDS in A-layout-friendly row-major [q][kv]
#pragma unroll
    for (int n = 0; n < 4; ++n)
#pragma unroll
      for (int j = 0; j < 4; ++j) {
        int qr = ((lane >> 4) << 2) + j;
        int cb = ((n << 4) + (lane & 15)) * 2;
        *(u16*)((char*)&Ps[w][0] + (qr << 7) + (cb ^ ((qr & 7) << 4))) = pb[n][j];
      }

    // O += P V : 4 d-tiles x 2 kv-k-steps
#pragma unroll
    for (int dt = 0; dt < 4; ++dt) {
      int d = (dt << 4) + (lane & 15);
      int qr = lane & 15;
#pragma unroll
      for (int ks = 0; ks < 2; ++ks) {
        int lb = (ks << 6) + ((lane >> 4) << 4);
        bf16x8 pf = *(const bf16x8*)((const char*)&Ps[w][0] + (qr << 7) +
                                     (lb ^ ((qr & 7) << 4)));
        bf16x8 vf =
            *(const bf16x8*)((const char*)Vt + (d << 7) + (lb ^ ((d & 7) << 4)));
        oacc[dt] = __builtin_amdgcn_mfma_f32_16x16x32_bf16(pf, vf, oacc[dt], 0, 0, 0);
      }
    }
  }

  // epilogue: normalize and write o in [B,N,H*Dh] layout (bf16)
#pragma unroll
  for (int j = 0; j < 4; ++j) lrow[j] = 1.f / lrow[j];
  const int orow0 = rowbase + (qt << 6) + (w << 4) + ((lane >> 4) << 2);
#pragma unroll
  for (int dt = 0; dt < 4; ++dt) {
    int col = qcol + (dt << 4) + (lane & 15);
#pragma unroll
    for (int j = 0; j < 4; ++j)
      ob[(size_t)(orow0 + j) * DIM_ + col] = f2bf(oacc[dt][j] * lrow[j]);
  }
}

// ---------------- launch ----------------
extern "C" void kernel_launch(void* const* d_in, const int* in_sizes, int n_in,
                              void* d_out, int out_size, void* d_ws, size_t ws_size,
                              hipStream_t stream) {
  const float* x = (const float*)d_in[0];
  const float* w_qkv = (const float*)d_in[1];
  const float* w_out = (const float*)d_in[2];
  const float* b_out = (const float*)d_in[3];

  u16* xb = (u16*)d_ws;                               // 8192*768
  u16* wqkvb = xb + (size_t)M_ * DIM_;                // 2304*768
  u16* woutb = wqkvb + (size_t)NQKV_ * DIM_;          // 768*768
  u16* qkvb = woutb + (size_t)DIM_ * DIM_;            // 8192*2304
  u16* obuf = qkvb + (size_t)M_ * NQKV_;              // 8192*768
  // total = 67.6 MB of workspace

  {
    int n4 = M_ * DIM_ / 4;
    cast_bf16_k<<<(n4 + 255) / 256, 256, 0, stream>>>(x, xb, n4);
  }
  {
    int n4 = NQKV_ * DIM_ / 4;
    cast_bf16_k<<<(n4 + 255) / 256, 256, 0, stream>>>(w_qkv, wqkvb, n4);
  }
  {
    int n4 = DIM_ * DIM_ / 4;
    cast_bf16_k<<<(n4 + 255) / 256, 256, 0, stream>>>(w_out, woutb, n4);
  }

  gemm_bt_k<true, false><<<dim3(NQKV_ / 128, M_ / 128), 256, 0, stream>>>(
      xb, wqkvb, (void*)qkvb, nullptr, DIM_, NQKV_);

  attn_k<<<dim3(B_ * H_ * 16), 256, 0, stream>>>(qkvb, obuf);

  gemm_bt_k<false, true><<<dim3(DIM_ / 128, M_ / 128), 256, 0, stream>>>(
      obuf, woutb, d_out, b_out, DIM_, DIM_);
}

// Round 4
// 228.728 us; speedup vs baseline: 1.1645x; 1.1645x over previous
//
#include <hip/hip_runtime.h>

#define B_ 8
#define N_ 1024
#define DIM_ 768
#define H_ 12
#define DH_ 64
#define M_ (B_ * N_)       // 8192
#define NQKV_ (3 * DIM_)   // 2304
#define SCL_ 0.18033688011112042f  // (1/sqrt(64)) * log2(e)

typedef unsigned short u16;
typedef unsigned int u32;
typedef __attribute__((ext_vector_type(8))) unsigned short u16x8;
typedef __attribute__((ext_vector_type(4))) unsigned short u16x4;
typedef __attribute__((ext_vector_type(8))) short bf16x8;
typedef __attribute__((ext_vector_type(4))) float f32x4;

__device__ __forceinline__ u16 f2bf(float f) {
  u32 u = __builtin_bit_cast(u32, f);
  u += 0x7fffu + ((u >> 16) & 1u);
  return (u16)(u >> 16);
}
__device__ __forceinline__ float bf2f(u16 v) {
  u32 u = ((u32)v) << 16;
  return __builtin_bit_cast(float, u);
}
__device__ __forceinline__ void async16(const void* g, void* l) {
  __builtin_amdgcn_global_load_lds(
      (const __attribute__((address_space(1))) unsigned int*)g,
      (__attribute__((address_space(3))) unsigned int*)l, 16, 0, 0);
}

// ---------------- cast fp32 -> bf16, vectorized x4 ----------------
__global__ __launch_bounds__(256) void cast_bf16_k(const float* __restrict__ in,
                                                   u16* __restrict__ out, int n4) {
  int i = blockIdx.x * 256 + threadIdx.x;
  if (i >= n4) return;
  float4 v = reinterpret_cast<const float4*>(in)[i];
  u16x4 o;
  o.x = f2bf(v.x); o.y = f2bf(v.y); o.z = f2bf(v.z); o.w = f2bf(v.w);
  reinterpret_cast<u16x4*>(out)[i] = o;
}

// ---------------- C = A * B^T  (A:[M,K], B:[N,K], both bf16 row-major) -----
// 128x128 tile, BK=32, 4 waves (2x2), 4x4 16x16x32 MFMA frags.
// VSPLIT: columns >=1536 (the V part of qkv) are written TRANSPOSED to
// vT[(b*H+h)*64+d][n] instead of the C matrix (feeds attention's V^T LDS).
template <bool OUT_BF16, bool BIAS, bool VSPLIT>
__global__ __launch_bounds__(256) void gemm_bt_k(
    const u16* __restrict__ A, const u16* __restrict__ Bm,
    void* __restrict__ Cv, const float* __restrict__ bias, int K, int ldc,
    u16* __restrict__ vT) {
  __shared__ u16 As[128 * 32];
  __shared__ u16 Bs[128 * 32];
  const int t = threadIdx.x;
  const int lane = t & 63;
  const int wid = t >> 6;
  const int brow = blockIdx.y << 7;
  const int bcol = blockIdx.x << 7;
  const int wrow = (wid >> 1) << 6;
  const int wcol = (wid & 1) << 6;

  f32x4 acc[4][4];
#pragma unroll
  for (int m = 0; m < 4; ++m)
#pragma unroll
    for (int n = 0; n < 4; ++n) acc[m][n] = (f32x4){0.f, 0.f, 0.f, 0.f};

  const int loff0 = t << 4, loff1 = (t + 256) << 4;
  const int r0 = loff0 >> 6, r1 = loff1 >> 6;
  const int s0 = ((((loff0 >> 4) & 3) ^ (r0 & 3)) << 3);
  const int s1 = ((((loff1 >> 4) & 3) ^ (r1 & 3)) << 3);
  const u16* gA0 = A + (size_t)(brow + r0) * K + s0;
  const u16* gA1 = A + (size_t)(brow + r1) * K + s1;
  const u16* gB0 = Bm + (size_t)(bcol + r0) * K + s0;
  const u16* gB1 = Bm + (size_t)(bcol + r1) * K + s1;
  char* lA = (char*)As;
  char* lB = (char*)Bs;

  const int kb = (lane >> 4) << 4;
  int aoff[4], boff[4];
#pragma unroll
  for (int m = 0; m < 4; ++m) {
    int ra = wrow + (m << 4) + (lane & 15);
    aoff[m] = (ra << 6) + (kb ^ ((ra & 3) << 4));
    int rb = wcol + (m << 4) + (lane & 15);
    boff[m] = (rb << 6) + (kb ^ ((rb & 3) << 4));
  }

  const int nkt = K >> 5;
  for (int kt = 0; kt < nkt; ++kt) {
    const int ko = kt << 5;
    async16(gA0 + ko, lA + loff0);
    async16(gA1 + ko, lA + loff1);
    async16(gB0 + ko, lB + loff0);
    async16(gB1 + ko, lB + loff1);
    __syncthreads();
    bf16x8 af[4], bfr[4];
#pragma unroll
    for (int m = 0; m < 4; ++m) af[m] = *(const bf16x8*)(lA + aoff[m]);
#pragma unroll
    for (int n = 0; n < 4; ++n) bfr[n] = *(const bf16x8*)(lB + boff[n]);
#pragma unroll
    for (int m = 0; m < 4; ++m)
#pragma unroll
      for (int n = 0; n < 4; ++n)
        acc[m][n] = __builtin_amdgcn_mfma_f32_16x16x32_bf16(af[m], bfr[n],
                                                            acc[m][n], 0, 0, 0);
    __syncthreads();
  }

  // epilogue: C/D layout col=lane&15, row=(lane>>4)*4+j  [m89/m91]
  const int crow = brow + wrow + ((lane >> 4) << 2);
  const int ccol0 = bcol + wcol + (lane & 15);
  if (VSPLIT && bcol >= 2 * DIM_) {
    // transposed V write: vT[(b*H+h)*64+d][n], 4 consecutive tokens -> 8B
#pragma unroll
    for (int n = 0; n < 4; ++n) {
      int colh = ccol0 + (n << 4) - 2 * DIM_;
      int h = colh >> 6, d = colh & 63;
#pragma unroll
      for (int m = 0; m < 4; ++m) {
        int row0 = crow + (m << 4);
        int bb = row0 >> 10, nn = row0 & 1023;
        int hbl = bb * H_ + h;
        uint2 pk;
        pk.x = (u32)f2bf(acc[m][n][0]) | ((u32)f2bf(acc[m][n][1]) << 16);
        pk.y = (u32)f2bf(acc[m][n][2]) | ((u32)f2bf(acc[m][n][3]) << 16);
        *(uint2*)(vT + (((size_t)(hbl * 64 + d)) << 10) + nn) = pk;
      }
    }
    return;
  }
#pragma unroll
  for (int m = 0; m < 4; ++m)
#pragma unroll
    for (int n = 0; n < 4; ++n) {
      int col = ccol0 + (n << 4);
      float bv = BIAS ? bias[col] : 0.f;
#pragma unroll
      for (int j = 0; j < 4; ++j) {
        int row = crow + (m << 4) + j;
        if (OUT_BF16)
          ((u16*)Cv)[(size_t)row * ldc + col] = f2bf(acc[m][n][j]);
        else
          ((float*)Cv)[(size_t)row * ldc + col] = acc[m][n][j] + bv;
      }
    }
}

// ---------------- fused flash attention, swapped-QK^T form ----------------
// block = 4 waves, 64 Q rows (16/wave); 16 KV tiles of 64.
// S^T = mfma(K, Q): lane holds S^T[kv=16n+4g+j][q=lane&15] -> kv reduction is
// 16 in-lane values + shfl_xor(16,32). P stored to per-wave LDS as [q][kv]
// with 4x ds_write_b64. K and V^T staged via global_load_lds(16B) with
// source-side XOR pre-swizzle (LDS dest linear; rule #21).
__global__ __launch_bounds__(256) void attn_k(const u16* __restrict__ qkv,
                                              const u16* __restrict__ vT,
                                              u16* __restrict__ ob) {
  __shared__ u16 Ks[64 * 64];      // [kv][d] rows 128B, swz ^((kv&7)<<4)
  __shared__ u16 Vt[64 * 64];      // [d][kv] rows 128B, swz ^((d&7)<<4)
  __shared__ u16 Ps[4][16 * 64];   // per-wave P [q][kv], swz ^((q&7)<<4)
  const int t = threadIdx.x;
  const int lane = t & 63;
  const int w = t >> 6;
  const int g = lane >> 4;
  const int q15 = lane & 15;

  // XCD-aware swizzle: 1536 blocks = 8 XCDs x 12 heads x 16 q-tiles;
  // all 16 q-tiles of a head (share K/V) land on one XCD.
  const int orig = blockIdx.x;
  const int sub = orig >> 3;
  const int hb = (orig & 7) * 12 + (sub >> 4);
  const int qt = sub & 15;
  const int b = hb / H_;
  const int h = hb - b * H_;
  const int rowbase = b * N_;
  const int qcol = h * DH_;
  const int kcol = DIM_ + qcol;

  // Q fragment (B-operand: col=lane&15=q, k=d=(lane>>4)*8+j+32ks), pre-scaled
  bf16x8 qf[2];
  {
    const int qrow = rowbase + (qt << 6) + (w << 4) + q15;
    const u16* src = qkv + (size_t)qrow * NQKV_ + qcol + (g << 3);
#pragma unroll
    for (int ks = 0; ks < 2; ++ks) {
      u16x8 raw = *(const u16x8*)(src + ks * 32);
      bf16x8 o;
#pragma unroll
      for (int j = 0; j < 8; ++j) o[j] = (short)f2bf(bf2f(raw[j]) * SCL_);
      qf[ks] = o;
    }
  }

  float mrow = -1e30f, lrow = 0.f;
  f32x4 oacc[4];
#pragma unroll
  for (int d = 0; d < 4; ++d) oacc[d] = (f32x4){0.f, 0.f, 0.f, 0.f};

  // staging: thread t owns LDS bytes t*16 (rows 0..31) and (t+256)*16
  // (rows 32..63); source chunk pre-swizzled: c' = c ^ (row&7).
  const int sr = t >> 3;
  const int c8 = t & 7;
  const int loff0 = t << 4, loff1 = (t + 256) << 4;
  const u16* kg0 = qkv + (size_t)(rowbase + sr) * NQKV_ + kcol + ((c8 ^ (sr & 7)) << 3);
  const u16* kg1 = qkv + (size_t)(rowbase + sr + 32) * NQKV_ + kcol + ((c8 ^ (sr & 7)) << 3);
  const u16* vg0 = vT + (((size_t)(hb * 64 + sr)) << 10) + ((c8 ^ (sr & 7)) << 3);
  const u16* vg1 = vT + (((size_t)(hb * 64 + sr + 32)) << 10) + ((c8 ^ (sr & 7)) << 3);
  char* lk = (char*)Ks;
  char* lv = (char*)Vt;
  char* lp = (char*)&Ps[w][0];

  for (int kv = 0; kv < 16; ++kv) {
    __syncthreads();  // prev tile's LDS reads done before restaging
    async16(kg0 + (size_t)kv * 64 * NQKV_, lk + loff0);
    async16(kg1 + (size_t)kv * 64 * NQKV_, lk + loff1);
    async16(vg0 + kv * 64, lv + loff0);
    async16(vg1 + kv * 64, lv + loff1);
    __syncthreads();  // vmcnt(0) drained by barrier -> staging complete

    // S^T = K Q^T : s[n] holds S^T[kv=16n+4g+j][q15]
    f32x4 s[4];
#pragma unroll
    for (int n = 0; n < 4; ++n) s[n] = (f32x4){0.f, 0.f, 0.f, 0.f};
#pragma unroll
    for (int n = 0; n < 4; ++n) {
      int rk = (n << 4) + q15;
#pragma unroll
      for (int ks = 0; ks < 2; ++ks) {
        int off = (rk << 7) + (((ks << 6) + (g << 4)) ^ ((rk & 7) << 4));
        bf16x8 kf = *(const bf16x8*)(lk + off);
        s[n] = __builtin_amdgcn_mfma_f32_16x16x32_bf16(kf, qf[ks], s[n], 0, 0, 0);
      }
    }

    // online softmax: per-lane scalar state (one q per lane)
    float mx = s[0][0];
#pragma unroll
    for (int n = 0; n < 4; ++n)
#pragma unroll
      for (int j = 0; j < 4; ++j) mx = fmaxf(mx, s[n][j]);
    mx = fmaxf(mx, __shfl_xor(mx, 16, 64));
    mx = fmaxf(mx, __shfl_xor(mx, 32, 64));
    float mn = fmaxf(mrow, mx);
    float al = exp2f(mrow - mn);
    mrow = mn;
    float p[4][4];
    float ps = 0.f;
#pragma unroll
    for (int n = 0; n < 4; ++n)
#pragma unroll
      for (int j = 0; j < 4; ++j) {
        p[n][j] = exp2f(s[n][j] - mn);
        ps += p[n][j];
      }
    ps += __shfl_xor(ps, 16, 64);
    ps += __shfl_xor(ps, 32, 64);
    lrow = lrow * al + ps;

    // rescale O (oacc rows are q=g*4+j; al lives at lane q)
    float alj[4];
#pragma unroll
    for (int j = 0; j < 4; ++j) alj[j] = __shfl(al, (g << 2) + j, 64);
#pragma unroll
    for (int d = 0; d < 4; ++d)
#pragma unroll
      for (int j = 0; j < 4; ++j) oacc[d][j] *= alj[j];

    // P -> per-wave LDS [q][kv]: lane's 16 values are kv=16n+4g+j at row q15
#pragma unroll
    for (int n = 0; n < 4; ++n) {
      uint2 pk;
      pk.x = (u32)f2bf(p[n][0]) | ((u32)f2bf(p[n][1]) << 16);
      pk.y = (u32)f2bf(p[n][2]) | ((u32)f2bf(p[n][3]) << 16);
      *(uint2*)(lp + (q15 << 7) + (((n << 5) + (g << 3)) ^ ((q15 & 7) << 4))) = pk;
    }

    // O += P V : A=P[q][kv] (row=q15), B=V^T[d][kv] (col=d)
    bf16x8 pf[2];
#pragma unroll
    for (int ks = 0; ks < 2; ++ks)
      pf[ks] = *(const bf16x8*)(lp + (q15 << 7) +
                                (((ks << 6) + (g << 4)) ^ ((q15 & 7) << 4)));
#pragma unroll
    for (int dt = 0; dt < 4; ++dt) {
      int d = (dt << 4) + q15;
#pragma unroll
      for (int ks = 0; ks < 2; ++ks) {
        bf16x8 vf = *(const bf16x8*)(lv + (d << 7) +
                                     (((ks << 6) + (g << 4)) ^ ((d & 7) << 4)));
        oacc[dt] = __builtin_amdgcn_mfma_f32_16x16x32_bf16(pf[ks], vf, oacc[dt], 0, 0, 0);
      }
    }
  }

  // epilogue: normalize, write o[token][h*64+d] (bf16)
  float rl = 1.f / lrow;
  float rlj[4];
#pragma unroll
  for (int j = 0; j < 4; ++j) rlj[j] = __shfl(rl, (g << 2) + j, 64);
  const int orow0 = rowbase + (qt << 6) + (w << 4) + (g << 2);
#pragma unroll
  for (int dt = 0; dt < 4; ++dt) {
    int col = qcol + (dt << 4) + q15;
#pragma unroll
    for (int j = 0; j < 4; ++j)
      ob[(size_t)(orow0 + j) * DIM_ + col] = f2bf(oacc[dt][j] * rlj[j]);
  }
}

// ---------------- launch ----------------
extern "C" void kernel_launch(void* const* d_in, const int* in_sizes, int n_in,
                              void* d_out, int out_size, void* d_ws, size_t ws_size,
                              hipStream_t stream) {
  const float* x = (const float*)d_in[0];
  const float* w_qkv = (const float*)d_in[1];
  const float* w_out = (const float*)d_in[2];
  const float* b_out = (const float*)d_in[3];

  u16* xb = (u16*)d_ws;                               // 8192*768
  u16* wqkvb = xb + (size_t)M_ * DIM_;                // 2304*768
  u16* woutb = wqkvb + (size_t)NQKV_ * DIM_;          // 768*768
  u16* qkvb = woutb + (size_t)DIM_ * DIM_;            // 8192*2304 (V third unused)
  u16* obuf = qkvb + (size_t)M_ * NQKV_;              // 8192*768
  u16* vT = obuf + (size_t)M_ * DIM_;                 // 96*64*1024 transposed V
  // total ~80.2 MB of workspace

  {
    int n4 = M_ * DIM_ / 4;
    cast_bf16_k<<<(n4 + 255) / 256, 256, 0, stream>>>(x, xb, n4);
  }
  {
    int n4 = NQKV_ * DIM_ / 4;
    cast_bf16_k<<<(n4 + 255) / 256, 256, 0, stream>>>(w_qkv, wqkvb, n4);
  }
  {
    int n4 = DIM_ * DIM_ / 4;
    cast_bf16_k<<<(n4 + 255) / 256, 256, 0, stream>>>(w_out, woutb, n4);
  }

  gemm_bt_k<true, false, true><<<dim3(NQKV_ / 128, M_ / 128), 256, 0, stream>>>(
      xb, wqkvb, (void*)qkvb, nullptr, DIM_, NQKV_, vT);

  attn_k<<<dim3(B_ * H_ * 16), 256, 0, stream>>>(qkvb, vT, obuf);

  gemm_bt_k<false, true, false><<<dim3(DIM_ / 128, M_ / 128), 256, 0, stream>>>(
      obuf, woutb, d_out, b_out, DIM_, DIM_, nullptr);
}

// Round 6
// 213.243 us; speedup vs baseline: 1.2490x; 1.0726x over previous
//
#include <hip/hip_runtime.h>

#define B_ 8
#define N_ 1024
#define DIM_ 768
#define H_ 12
#define DH_ 64
#define M_ (B_ * N_)       // 8192
#define NQKV_ (3 * DIM_)   // 2304
#define SCL_ 0.18033688011112042f  // (1/sqrt(64)) * log2(e)

typedef unsigned short u16;
typedef unsigned int u32;
typedef __attribute__((ext_vector_type(8))) unsigned short u16x8;
typedef __attribute__((ext_vector_type(4))) unsigned short u16x4;
typedef __attribute__((ext_vector_type(8))) short bf16x8;
typedef __attribute__((ext_vector_type(4))) float f32x4;

__device__ __forceinline__ u16 f2bf(float f) {
  u32 u = __builtin_bit_cast(u32, f);
  u += 0x7fffu + ((u >> 16) & 1u);
  return (u16)(u >> 16);
}
__device__ __forceinline__ float bf2f(u16 v) {
  u32 u = ((u32)v) << 16;
  return __builtin_bit_cast(float, u);
}
__device__ __forceinline__ u32 cvtpk_bf16(float lo, float hi) {
  u32 r;
  asm("v_cvt_pk_bf16_f32 %0, %1, %2" : "=v"(r) : "v"(lo), "v"(hi));
  return r;
}
__device__ __forceinline__ void async16(const void* g, void* l) {
  __builtin_amdgcn_global_load_lds(
      (const __attribute__((address_space(1))) unsigned int*)g,
      (__attribute__((address_space(3))) unsigned int*)l, 16, 0, 0);
}

// ---------------- cast fp32 -> bf16, vectorized x4 ----------------
__global__ __launch_bounds__(256) void cast_bf16_k(const float* __restrict__ in,
                                                   u16* __restrict__ out, int n4) {
  int i = blockIdx.x * 256 + threadIdx.x;
  if (i >= n4) return;
  float4 v = reinterpret_cast<const float4*>(in)[i];
  u16x4 o;
  o.x = f2bf(v.x); o.y = f2bf(v.y); o.z = f2bf(v.z); o.w = f2bf(v.w);
  reinterpret_cast<u16x4*>(out)[i] = o;
}

// ---------------- C = A * B^T  (A:[M,K], B:[N,K], both bf16 row-major) -----
// 128x128 tile, BK=32, 4 waves (2x2), 4x4 16x16x32 MFMA frags.
// VSPLIT: columns >=1536 (the V part of qkv) are written TRANSPOSED to
// vT[(b*H+h)*64+d][n] instead of the C matrix (feeds attention's V^T LDS).
template <bool OUT_BF16, bool BIAS, bool VSPLIT>
__global__ __launch_bounds__(256) void gemm_bt_k(
    const u16* __restrict__ A, const u16* __restrict__ Bm,
    void* __restrict__ Cv, const float* __restrict__ bias, int K, int ldc,
    u16* __restrict__ vT) {
  __shared__ u16 As[128 * 32];
  __shared__ u16 Bs[128 * 32];
  const int t = threadIdx.x;
  const int lane = t & 63;
  const int wid = t >> 6;
  const int brow = blockIdx.y << 7;
  const int bcol = blockIdx.x << 7;
  const int wrow = (wid >> 1) << 6;
  const int wcol = (wid & 1) << 6;

  f32x4 acc[4][4];
#pragma unroll
  for (int m = 0; m < 4; ++m)
#pragma unroll
    for (int n = 0; n < 4; ++n) acc[m][n] = (f32x4){0.f, 0.f, 0.f, 0.f};

  const int loff0 = t << 4, loff1 = (t + 256) << 4;
  const int r0 = loff0 >> 6, r1 = loff1 >> 6;
  const int s0 = ((((loff0 >> 4) & 3) ^ (r0 & 3)) << 3);
  const int s1 = ((((loff1 >> 4) & 3) ^ (r1 & 3)) << 3);
  const u16* gA0 = A + (size_t)(brow + r0) * K + s0;
  const u16* gA1 = A + (size_t)(brow + r1) * K + s1;
  const u16* gB0 = Bm + (size_t)(bcol + r0) * K + s0;
  const u16* gB1 = Bm + (size_t)(bcol + r1) * K + s1;
  char* lA = (char*)As;
  char* lB = (char*)Bs;

  const int kb = (lane >> 4) << 4;
  int aoff[4], boff[4];
#pragma unroll
  for (int m = 0; m < 4; ++m) {
    int ra = wrow + (m << 4) + (lane & 15);
    aoff[m] = (ra << 6) + (kb ^ ((ra & 3) << 4));
    int rb = wcol + (m << 4) + (lane & 15);
    boff[m] = (rb << 6) + (kb ^ ((rb & 3) << 4));
  }

  const int nkt = K >> 5;
  for (int kt = 0; kt < nkt; ++kt) {
    const int ko = kt << 5;
    async16(gA0 + ko, lA + loff0);
    async16(gA1 + ko, lA + loff1);
    async16(gB0 + ko, lB + loff0);
    async16(gB1 + ko, lB + loff1);
    __syncthreads();
    bf16x8 af[4], bfr[4];
#pragma unroll
    for (int m = 0; m < 4; ++m) af[m] = *(const bf16x8*)(lA + aoff[m]);
#pragma unroll
    for (int n = 0; n < 4; ++n) bfr[n] = *(const bf16x8*)(lB + boff[n]);
#pragma unroll
    for (int m = 0; m < 4; ++m)
#pragma unroll
      for (int n = 0; n < 4; ++n)
        acc[m][n] = __builtin_amdgcn_mfma_f32_16x16x32_bf16(af[m], bfr[n],
                                                            acc[m][n], 0, 0, 0);
    __syncthreads();
  }

  // epilogue: C/D layout col=lane&15, row=(lane>>4)*4+j  [m89/m91]
  const int crow = brow + wrow + ((lane >> 4) << 2);
  const int ccol0 = bcol + wcol + (lane & 15);
  if (VSPLIT && bcol >= 2 * DIM_) {
    // transposed V write: vT[(b*H+h)*64+d][n], 4 consecutive tokens -> 8B
#pragma unroll
    for (int n = 0; n < 4; ++n) {
      int colh = ccol0 + (n << 4) - 2 * DIM_;
      int h = colh >> 6, d = colh & 63;
#pragma unroll
      for (int m = 0; m < 4; ++m) {
        int row0 = crow + (m << 4);
        int bb = row0 >> 10, nn = row0 & 1023;
        int hbl = bb * H_ + h;
        uint2 pk;
        pk.x = (u32)f2bf(acc[m][n][0]) | ((u32)f2bf(acc[m][n][1]) << 16);
        pk.y = (u32)f2bf(acc[m][n][2]) | ((u32)f2bf(acc[m][n][3]) << 16);
        *(uint2*)(vT + (((size_t)(hbl * 64 + d)) << 10) + nn) = pk;
      }
    }
    return;
  }
#pragma unroll
  for (int m = 0; m < 4; ++m)
#pragma unroll
    for (int n = 0; n < 4; ++n) {
      int col = ccol0 + (n << 4);
      float bv = BIAS ? bias[col] : 0.f;
#pragma unroll
      for (int j = 0; j < 4; ++j) {
        int row = crow + (m << 4) + j;
        if (OUT_BF16)
          ((u16*)Cv)[(size_t)row * ldc + col] = f2bf(acc[m][n][j]);
        else
          ((float*)Cv)[(size_t)row * ldc + col] = acc[m][n][j] + bv;
      }
    }
}

// ---------------- fused flash attention, swapped-QK^T, 2-phase dbuf -------
// block = 4 waves, 64 Q rows (16/wave); 16 KV tiles of 64.
// K/V double-buffered in LDS; tile t+1's global_load_lds issued at the top
// of iter t, drained by vmcnt(0)+raw-barrier at the END of iter t (latency
// hidden under compute). One barrier per tile. Defer-max (THR=8) skips the
// O-rescale on most tiles. P packed with v_cvt_pk_bf16_f32.
__global__ __launch_bounds__(256) void attn_k(const u16* __restrict__ qkv,
                                              const u16* __restrict__ vT,
                                              u16* __restrict__ ob) {
  __shared__ u16 Ks[2][64 * 64];   // [buf][kv][d] rows 128B, swz ^((kv&7)<<4)
  __shared__ u16 Vt[2][64 * 64];   // [buf][d][kv] rows 128B, swz ^((d&7)<<4)
  __shared__ u16 Ps[4][16 * 64];   // per-wave P [q][kv], swz ^((q&7)<<4)
  const int t = threadIdx.x;
  const int lane = t & 63;
  const int w = t >> 6;
  const int g = lane >> 4;
  const int q15 = lane & 15;

  // XCD-aware swizzle: 1536 blocks = 8 XCDs x 12 heads x 16 q-tiles
  const int orig = blockIdx.x;
  const int sub = orig >> 3;
  const int hb = (orig & 7) * 12 + (sub >> 4);
  const int qt = sub & 15;
  const int b = hb / H_;
  const int h = hb - b * H_;
  const int rowbase = b * N_;
  const int qcol = h * DH_;
  const int kcol = DIM_ + qcol;

  // Q fragment (B-operand: col=q15, k=d=g*8+j+32ks), pre-scaled by SCL_
  bf16x8 qf[2];
  {
    const int qrow = rowbase + (qt << 6) + (w << 4) + q15;
    const u16* src = qkv + (size_t)qrow * NQKV_ + qcol + (g << 3);
#pragma unroll
    for (int ks = 0; ks < 2; ++ks) {
      u16x8 raw = *(const u16x8*)(src + ks * 32);
      bf16x8 o;
#pragma unroll
      for (int j = 0; j < 8; ++j) o[j] = (short)f2bf(bf2f(raw[j]) * SCL_);
      qf[ks] = o;
    }
  }

  float mrow = -1e30f, lrow = 0.f;
  f32x4 oacc[4];
#pragma unroll
  for (int d = 0; d < 4; ++d) oacc[d] = (f32x4){0.f, 0.f, 0.f, 0.f};

  // staging: thread t owns LDS bytes t*16 (rows 0..31) and (t+256)*16
  // (rows 32..63); source chunk pre-swizzled: c' = c ^ (row&7)  (rule #21).
  const int sr = t >> 3;
  const int c8 = t & 7;
  const int loff0 = t << 4, loff1 = (t + 256) << 4;
  const u16* kg0 = qkv + (size_t)(rowbase + sr) * NQKV_ + kcol + ((c8 ^ (sr & 7)) << 3);
  const u16* kg1 = qkv + (size_t)(rowbase + sr + 32) * NQKV_ + kcol + ((c8 ^ (sr & 7)) << 3);
  const u16* vg0 = vT + (((size_t)(hb * 64 + sr)) << 10) + ((c8 ^ (sr & 7)) << 3);
  const u16* vg1 = vT + (((size_t)(hb * 64 + sr + 32)) << 10) + ((c8 ^ (sr & 7)) << 3);
  char* lk0 = (char*)Ks;   // buffer stride 8192 B
  char* lv0 = (char*)Vt;
  char* lp = (char*)Ps + (w << 11);

  // loop-invariant read offsets (note: rk&7 == d&7 == q15&7)
  const int rowB = q15 << 7;
  const int xsw = (q15 & 7) << 4;
  const int x0 = (g << 4) ^ xsw;
  const int x1 = (64 + (g << 4)) ^ xsw;

  // prologue: stage tile 0 -> buf 0
  async16(kg0, lk0 + loff0);
  async16(kg1, lk0 + loff1);
  async16(vg0, lv0 + loff0);
  async16(vg1, lv0 + loff1);
  asm volatile("s_waitcnt vmcnt(0)" ::: "memory");
  __builtin_amdgcn_s_barrier();

  for (int kv = 0; kv < 16; ++kv) {
    const int cur = kv & 1;
    // issue next tile's loads into the other buffer (fly under compute)
    if (kv < 15) {
      const int nb = (cur ^ 1) << 13;
      const size_t kofs = (size_t)(kv + 1) * 64;
      async16(kg0 + kofs * NQKV_, lk0 + nb + loff0);
      async16(kg1 + kofs * NQKV_, lk0 + nb + loff1);
      async16(vg0 + kofs, lv0 + nb + loff0);
      async16(vg1 + kofs, lv0 + nb + loff1);
    }
    const char* lkc = lk0 + (cur << 13);
    const char* lvc = lv0 + (cur << 13);

    // S^T = K Q^T : s4[n] holds S^T[kv=16n+4g+j][q15]
    f32x4 s4[4];
#pragma unroll
    for (int n = 0; n < 4; ++n) s4[n] = (f32x4){0.f, 0.f, 0.f, 0.f};
    __builtin_amdgcn_s_setprio(1);
#pragma unroll
    for (int n = 0; n < 4; ++n) {
      bf16x8 kf0 = *(const bf16x8*)(lkc + (n << 11) + rowB + x0);
      s4[n] = __builtin_amdgcn_mfma_f32_16x16x32_bf16(kf0, qf[0], s4[n], 0, 0, 0);
      bf16x8 kf1 = *(const bf16x8*)(lkc + (n << 11) + rowB + x1);
      s4[n] = __builtin_amdgcn_mfma_f32_16x16x32_bf16(kf1, qf[1], s4[n], 0, 0, 0);
    }
    __builtin_amdgcn_s_setprio(0);

    // tile max (tree; 4 lanes sharing q15 combined via xor16/xor32)
    float mx;
    {
      float a0 = fmaxf(fmaxf(s4[0][0], s4[0][1]), fmaxf(s4[0][2], s4[0][3]));
      float a1 = fmaxf(fmaxf(s4[1][0], s4[1][1]), fmaxf(s4[1][2], s4[1][3]));
      float a2 = fmaxf(fmaxf(s4[2][0], s4[2][1]), fmaxf(s4[2][2], s4[2][3]));
      float a3 = fmaxf(fmaxf(s4[3][0], s4[3][1]), fmaxf(s4[3][2], s4[3][3]));
      mx = fmaxf(fmaxf(a0, a1), fmaxf(a2, a3));
      mx = fmaxf(mx, __shfl_xor(mx, 16, 64));
      mx = fmaxf(mx, __shfl_xor(mx, 32, 64));
    }
    // defer-max: rescale only when the running max grew by > 8 (exp2 domain)
    if (!__all(mx - mrow <= 8.f)) {
      float mn = fmaxf(mrow, mx);
      float al = __builtin_amdgcn_exp2f(mrow - mn);
      mrow = mn;
      lrow *= al;
      float alj[4];
#pragma unroll
      for (int j = 0; j < 4; ++j) alj[j] = __shfl(al, (g << 2) + j, 64);
#pragma unroll
      for (int d = 0; d < 4; ++d)
#pragma unroll
        for (int j = 0; j < 4; ++j) oacc[d][j] *= alj[j];
    }

    float p[4][4];
    float ps = 0.f;
#pragma unroll
    for (int n = 0; n < 4; ++n)
#pragma unroll
      for (int j = 0; j < 4; ++j) {
        p[n][j] = __builtin_amdgcn_exp2f(s4[n][j] - mrow);
        ps += p[n][j];
      }
    ps += __shfl_xor(ps, 16, 64);
    ps += __shfl_xor(ps, 32, 64);
    lrow += ps;

    // P -> per-wave LDS [q][kv] via cvt_pk (lane's kv=16n+4g+j at row q15)
#pragma unroll
    for (int n = 0; n < 4; ++n) {
      uint2 pk;
      pk.x = cvtpk_bf16(p[n][0], p[n][1]);
      pk.y = cvtpk_bf16(p[n][2], p[n][3]);
      *(uint2*)(lp + rowB + (((n << 5) + (g << 3)) ^ xsw)) = pk;
    }

    // O += P V : A=P[q][kv] (row=q15), B=V^T[d][kv] (col=d)
    bf16x8 pf0 = *(const bf16x8*)(lp + rowB + x0);
    bf16x8 pf1 = *(const bf16x8*)(lp + rowB + x1);
    __builtin_amdgcn_s_setprio(1);
#pragma unroll
    for (int dt = 0; dt < 4; ++dt) {
      bf16x8 vf0 = *(const bf16x8*)(lvc + (dt << 11) + rowB + x0);
      oacc[dt] = __builtin_amdgcn_mfma_f32_16x16x32_bf16(pf0, vf0, oacc[dt], 0, 0, 0);
      bf16x8 vf1 = *(const bf16x8*)(lvc + (dt << 11) + rowB + x1);
      oacc[dt] = __builtin_amdgcn_mfma_f32_16x16x32_bf16(pf1, vf1, oacc[dt], 0, 0, 0);
    }
    __builtin_amdgcn_s_setprio(0);

    // drain this iter's prefetch (had all of compute to land), then sync.
    asm volatile("s_waitcnt vmcnt(0)" ::: "memory");
    __builtin_amdgcn_s_barrier();
    __builtin_amdgcn_sched_barrier(0);
  }

  // epilogue: normalize, write o[token][h*64+d] (bf16)
  float rl = 1.f / lrow;
  float rlj[4];
#pragma unroll
  for (int j = 0; j < 4; ++j) rlj[j] = __shfl(rl, (g << 2) + j, 64);
  const int orow0 = rowbase + (qt << 6) + (w << 4) + (g << 2);
#pragma unroll
  for (int dt = 0; dt < 4; ++dt) {
    int col = qcol + (dt << 4) + q15;
#pragma unroll
    for (int j = 0; j < 4; ++j)
      ob[(size_t)(orow0 + j) * DIM_ + col] = f2bf(oacc[dt][j] * rlj[j]);
  }
}

// ---------------- launch ----------------
extern "C" void kernel_launch(void* const* d_in, const int* in_sizes, int n_in,
                              void* d_out, int out_size, void* d_ws, size_t ws_size,
                              hipStream_t stream) {
  const float* x = (const float*)d_in[0];
  const float* w_qkv = (const float*)d_in[1];
  const float* w_out = (const float*)d_in[2];
  const float* b_out = (const float*)d_in[3];

  u16* xb = (u16*)d_ws;                               // 8192*768
  u16* wqkvb = xb + (size_t)M_ * DIM_;                // 2304*768
  u16* woutb = wqkvb + (size_t)NQKV_ * DIM_;          // 768*768
  u16* qkvb = woutb + (size_t)DIM_ * DIM_;            // 8192*2304 (V third unused)
  u16* obuf = qkvb + (size_t)M_ * NQKV_;              // 8192*768
  u16* vT = obuf + (size_t)M_ * DIM_;                 // 96*64*1024 transposed V
  // total ~80.2 MB of workspace

  {
    int n4 = M_ * DIM_ / 4;
    cast_bf16_k<<<(n4 + 255) / 256, 256, 0, stream>>>(x, xb, n4);
  }
  {
    int n4 = NQKV_ * DIM_ / 4;
    cast_bf16_k<<<(n4 + 255) / 256, 256, 0, stream>>>(w_qkv, wqkvb, n4);
  }
  {
    int n4 = DIM_ * DIM_ / 4;
    cast_bf16_k<<<(n4 + 255) / 256, 256, 0, stream>>>(w_out, woutb, n4);
  }

  gemm_bt_k<true, false, true><<<dim3(NQKV_ / 128, M_ / 128), 256, 0, stream>>>(
      xb, wqkvb, (void*)qkvb, nullptr, DIM_, NQKV_, vT);

  attn_k<<<dim3(B_ * H_ * 16), 256, 0, stream>>>(qkvb, vT, obuf);

  gemm_bt_k<false, true, false><<<dim3(DIM_ / 128, M_ / 128), 256, 0, stream>>>(
      obuf, woutb, d_out, b_out, DIM_, DIM_, nullptr);
}

// Round 7
// 211.555 us; speedup vs baseline: 1.2590x; 1.0080x over previous
//
#include <hip/hip_runtime.h>

#define B_ 8
#define N_ 1024
#define DIM_ 768
#define H_ 12
#define DH_ 64
#define M_ (B_ * N_)       // 8192
#define NQKV_ (3 * DIM_)   // 2304
#define SCL_ 0.18033688011112042f  // (1/sqrt(64)) * log2(e)

typedef unsigned short u16;
typedef unsigned int u32;
typedef __attribute__((ext_vector_type(8))) unsigned short u16x8;
typedef __attribute__((ext_vector_type(4))) unsigned short u16x4;
typedef __attribute__((ext_vector_type(8))) short bf16x8;
typedef __attribute__((ext_vector_type(4))) float f32x4;

__device__ __forceinline__ u16 f2bf(float f) {
  u32 u = __builtin_bit_cast(u32, f);
  u += 0x7fffu + ((u >> 16) & 1u);
  return (u16)(u >> 16);
}
__device__ __forceinline__ float bf2f(u16 v) {
  u32 u = ((u32)v) << 16;
  return __builtin_bit_cast(float, u);
}
__device__ __forceinline__ u32 cvtpk_bf16(float lo, float hi) {
  u32 r;
  asm("v_cvt_pk_bf16_f32 %0, %1, %2" : "=v"(r) : "v"(lo), "v"(hi));
  return r;
}
__device__ __forceinline__ void async16(const void* g, void* l) {
  __builtin_amdgcn_global_load_lds(
      (const __attribute__((address_space(1))) unsigned int*)g,
      (__attribute__((address_space(3))) unsigned int*)l, 16, 0, 0);
}
#define VMCNT0_BARRIER()                                \
  asm volatile("s_waitcnt vmcnt(0)" ::: "memory");      \
  __builtin_amdgcn_s_barrier();                         \
  __builtin_amdgcn_sched_barrier(0)

// ---------------- cast fp32 -> bf16, vectorized x4 ----------------
__global__ __launch_bounds__(256) void cast_bf16_k(const float* __restrict__ in,
                                                   u16* __restrict__ out, int n4) {
  int i = blockIdx.x * 256 + threadIdx.x;
  if (i >= n4) return;
  float4 v = reinterpret_cast<const float4*>(in)[i];
  u16x4 o;
  o.x = f2bf(v.x); o.y = f2bf(v.y); o.z = f2bf(v.z); o.w = f2bf(v.w);
  reinterpret_cast<u16x4*>(out)[i] = o;
}

// ---------------- GEMM K-step compute (buffer offset is compile-time) -----
template <int BUFO>
__device__ __forceinline__ void gemm_step(const char* lA, const char* lB,
                                          const int (&aoff)[4],
                                          const int (&boff)[4],
                                          f32x4 (&acc)[4][4]) {
  bf16x8 af[4], bfr[4];
#pragma unroll
  for (int m = 0; m < 4; ++m) af[m] = *(const bf16x8*)(lA + BUFO + aoff[m]);
#pragma unroll
  for (int n = 0; n < 4; ++n) bfr[n] = *(const bf16x8*)(lB + BUFO + boff[n]);
#pragma unroll
  for (int m = 0; m < 4; ++m)
#pragma unroll
    for (int n = 0; n < 4; ++n)
      acc[m][n] = __builtin_amdgcn_mfma_f32_16x16x32_bf16(af[m], bfr[n],
                                                          acc[m][n], 0, 0, 0);
}

// ---------------- C = A * B^T  (A:[M,K], B:[N,K], both bf16 row-major) -----
// 128x128 tile, BK=32, 4 waves (2x2), 4x4 16x16x32 MFMA frags.
// 2-phase LDS double-buffer: next K-tile's global_load_lds issued before
// compute, drained at end of phase (loads fly under MFMA).
// VSPLIT: columns >=1536 (the V part of qkv) are written TRANSPOSED to
// vT[(b*H+h)*64+d][n] instead of the C matrix (feeds attention's V^T LDS).
template <bool OUT_BF16, bool BIAS, bool VSPLIT>
__global__ __launch_bounds__(256) void gemm_bt_k(
    const u16* __restrict__ A, const u16* __restrict__ Bm,
    void* __restrict__ Cv, const float* __restrict__ bias, int K, int ldc,
    u16* __restrict__ vT) {
  __shared__ u16 As[2][128 * 32];   // 8192 B per buffer
  __shared__ u16 Bs[2][128 * 32];
  const int t = threadIdx.x;
  const int lane = t & 63;
  const int wid = t >> 6;
  const int brow = blockIdx.y << 7;
  const int bcol = blockIdx.x << 7;
  const int wrow = (wid >> 1) << 6;
  const int wcol = (wid & 1) << 6;

  f32x4 acc[4][4];
#pragma unroll
  for (int m = 0; m < 4; ++m)
#pragma unroll
    for (int n = 0; n < 4; ++n) acc[m][n] = (f32x4){0.f, 0.f, 0.f, 0.f};

  const int loff0 = t << 4, loff1 = (t + 256) << 4;
  const int r0 = loff0 >> 6, r1 = loff1 >> 6;
  const int s0 = ((((loff0 >> 4) & 3) ^ (r0 & 3)) << 3);
  const int s1 = ((((loff1 >> 4) & 3) ^ (r1 & 3)) << 3);
  const u16* pA0 = A + (size_t)(brow + r0) * K + s0;
  const u16* pA1 = A + (size_t)(brow + r1) * K + s1;
  const u16* pB0 = Bm + (size_t)(bcol + r0) * K + s0;
  const u16* pB1 = Bm + (size_t)(bcol + r1) * K + s1;
  char* lA = (char*)As;
  char* lB = (char*)Bs;

#define GSTAGE(BUFO)                              \
  do {                                            \
    async16(pA0, lA + (BUFO) + loff0);            \
    async16(pA1, lA + (BUFO) + loff1);            \
    async16(pB0, lB + (BUFO) + loff0);            \
    async16(pB1, lB + (BUFO) + loff1);            \
    pA0 += 32; pA1 += 32; pB0 += 32; pB1 += 32;   \
  } while (0)

  const int kb = (lane >> 4) << 4;
  int aoff[4], boff[4];
#pragma unroll
  for (int m = 0; m < 4; ++m) {
    int ra = wrow + (m << 4) + (lane & 15);
    aoff[m] = (ra << 6) + (kb ^ ((ra & 3) << 4));
    int rb = wcol + (m << 4) + (lane & 15);
    boff[m] = (rb << 6) + (kb ^ ((rb & 3) << 4));
  }

  const int nkt = K >> 5;  // 24 for K=768 (even)
  GSTAGE(0);               // K-tile 0 -> buf0
  VMCNT0_BARRIER();
  for (int kt = 0; kt < nkt; kt += 2) {
    // phase 0: compute buf0 (tile kt), prefetch tile kt+1 -> buf1
    GSTAGE(8192);
    gemm_step<0>(lA, lB, aoff, boff, acc);
    VMCNT0_BARRIER();
    // phase 1: compute buf1 (tile kt+1), prefetch tile kt+2 -> buf0
    if (kt + 2 < nkt) GSTAGE(0);
    gemm_step<8192>(lA, lB, aoff, boff, acc);
    VMCNT0_BARRIER();
  }
#undef GSTAGE

  // epilogue: C/D layout col=lane&15, row=(lane>>4)*4+j  [m89/m91]
  const int crow = brow + wrow + ((lane >> 4) << 2);
  const int ccol0 = bcol + wcol + (lane & 15);
  if (VSPLIT && bcol >= 2 * DIM_) {
    // transposed V write: vT[(b*H+h)*64+d][n], 4 consecutive tokens -> 8B
#pragma unroll
    for (int n = 0; n < 4; ++n) {
      int colh = ccol0 + (n << 4) - 2 * DIM_;
      int h = colh >> 6, d = colh & 63;
#pragma unroll
      for (int m = 0; m < 4; ++m) {
        int row0 = crow + (m << 4);
        int bb = row0 >> 10, nn = row0 & 1023;
        int hbl = bb * H_ + h;
        uint2 pk;
        pk.x = (u32)f2bf(acc[m][n][0]) | ((u32)f2bf(acc[m][n][1]) << 16);
        pk.y = (u32)f2bf(acc[m][n][2]) | ((u32)f2bf(acc[m][n][3]) << 16);
        *(uint2*)(vT + (((size_t)(hbl * 64 + d)) << 10) + nn) = pk;
      }
    }
    return;
  }
#pragma unroll
  for (int m = 0; m < 4; ++m)
#pragma unroll
    for (int n = 0; n < 4; ++n) {
      int col = ccol0 + (n << 4);
      float bv = BIAS ? bias[col] : 0.f;
#pragma unroll
      for (int j = 0; j < 4; ++j) {
        int row = crow + (m << 4) + j;
        if (OUT_BF16)
          ((u16*)Cv)[(size_t)row * ldc + col] = f2bf(acc[m][n][j]);
        else
          ((float*)Cv)[(size_t)row * ldc + col] = acc[m][n][j] + bv;
      }
    }
}

// ---------------- attention tile (buffer offsets compile-time) ------------
template <int KOFF, int VOFF>
__device__ __forceinline__ void attn_tile(const char* lk0, const char* lv0,
                                          char* lp, const bf16x8 (&qf)[2],
                                          f32x4 (&oacc)[4], float& mrow,
                                          float& lrow, const int rowB,
                                          const int xsw, const int x0,
                                          const int x1, const int g) {
  // S^T = K Q^T : s4[n] holds S^T[kv=16n+4g+j][q=lane&15]
  f32x4 s4[4];
#pragma unroll
  for (int n = 0; n < 4; ++n) s4[n] = (f32x4){0.f, 0.f, 0.f, 0.f};
  __builtin_amdgcn_s_setprio(1);
#pragma unroll
  for (int n = 0; n < 4; ++n) {
    bf16x8 kf0 = *(const bf16x8*)(lk0 + KOFF + (n << 11) + rowB + x0);
    s4[n] = __builtin_amdgcn_mfma_f32_16x16x32_bf16(kf0, qf[0], s4[n], 0, 0, 0);
    bf16x8 kf1 = *(const bf16x8*)(lk0 + KOFF + (n << 11) + rowB + x1);
    s4[n] = __builtin_amdgcn_mfma_f32_16x16x32_bf16(kf1, qf[1], s4[n], 0, 0, 0);
  }
  __builtin_amdgcn_s_setprio(0);

  // tile max (tree; lanes sharing q combined via xor16/xor32)
  float mx;
  {
    float a0 = fmaxf(fmaxf(s4[0][0], s4[0][1]), fmaxf(s4[0][2], s4[0][3]));
    float a1 = fmaxf(fmaxf(s4[1][0], s4[1][1]), fmaxf(s4[1][2], s4[1][3]));
    float a2 = fmaxf(fmaxf(s4[2][0], s4[2][1]), fmaxf(s4[2][2], s4[2][3]));
    float a3 = fmaxf(fmaxf(s4[3][0], s4[3][1]), fmaxf(s4[3][2], s4[3][3]));
    mx = fmaxf(fmaxf(a0, a1), fmaxf(a2, a3));
    mx = fmaxf(mx, __shfl_xor(mx, 16, 64));
    mx = fmaxf(mx, __shfl_xor(mx, 32, 64));
  }
  // defer-max: rescale only when the running max grew by > 8 (exp2 domain)
  if (!__all(mx - mrow <= 8.f)) {
    float mn = fmaxf(mrow, mx);
    float al = __builtin_amdgcn_exp2f(mrow - mn);
    mrow = mn;
    lrow *= al;
    float alj[4];
#pragma unroll
    for (int j = 0; j < 4; ++j) alj[j] = __shfl(al, (g << 2) + j, 64);
#pragma unroll
    for (int d = 0; d < 4; ++d)
#pragma unroll
      for (int j = 0; j < 4; ++j) oacc[d][j] *= alj[j];
  }

  float p[4][4];
  float ps = 0.f;
#pragma unroll
  for (int n = 0; n < 4; ++n)
#pragma unroll
    for (int j = 0; j < 4; ++j) {
      p[n][j] = __builtin_amdgcn_exp2f(s4[n][j] - mrow);
      ps += p[n][j];
    }
  ps += __shfl_xor(ps, 16, 64);
  ps += __shfl_xor(ps, 32, 64);
  lrow += ps;

  // P -> per-wave LDS [q][kv] via cvt_pk (lane's kv=16n+4g+j at row q)
#pragma unroll
  for (int n = 0; n < 4; ++n) {
    uint2 pk;
    pk.x = cvtpk_bf16(p[n][0], p[n][1]);
    pk.y = cvtpk_bf16(p[n][2], p[n][3]);
    *(uint2*)(lp + rowB + (((n << 5) + (g << 3)) ^ xsw)) = pk;
  }

  // O += P V : A=P[q][kv] (row=q), B=V^T[d][kv] (col=d)
  bf16x8 pf0 = *(const bf16x8*)(lp + rowB + x0);
  bf16x8 pf1 = *(const bf16x8*)(lp + rowB + x1);
  __builtin_amdgcn_s_setprio(1);
#pragma unroll
  for (int dt = 0; dt < 4; ++dt) {
    bf16x8 vf0 = *(const bf16x8*)(lv0 + VOFF + (dt << 11) + rowB + x0);
    oacc[dt] = __builtin_amdgcn_mfma_f32_16x16x32_bf16(pf0, vf0, oacc[dt], 0, 0, 0);
    bf16x8 vf1 = *(const bf16x8*)(lv0 + VOFF + (dt << 11) + rowB + x1);
    oacc[dt] = __builtin_amdgcn_mfma_f32_16x16x32_bf16(pf1, vf1, oacc[dt], 0, 0, 0);
  }
  __builtin_amdgcn_s_setprio(0);
}

// ---------------- fused flash attention, swapped-QK^T, 2-phase dbuf -------
// block = 4 waves, 64 Q rows (16/wave); 16 KV tiles of 64, unrolled x2 so
// all LDS buffer offsets are compile-time immediates; staging pointers are
// pure increments (no per-tile multiplies).
__global__ __launch_bounds__(256) void attn_k(const u16* __restrict__ qkv,
                                              const u16* __restrict__ vT,
                                              u16* __restrict__ ob) {
  __shared__ u16 Ks[2][64 * 64];   // [buf][kv][d] rows 128B, swz ^((kv&7)<<4)
  __shared__ u16 Vt[2][64 * 64];   // [buf][d][kv] rows 128B, swz ^((d&7)<<4)
  __shared__ u16 Ps[4][16 * 64];   // per-wave P [q][kv], swz ^((q&7)<<4)
  const int t = threadIdx.x;
  const int lane = t & 63;
  const int w = t >> 6;
  const int g = lane >> 4;
  const int q15 = lane & 15;

  // XCD-aware swizzle: 1536 blocks = 8 XCDs x 12 heads x 16 q-tiles
  const int orig = blockIdx.x;
  const int sub = orig >> 3;
  const int hb = (orig & 7) * 12 + (sub >> 4);
  const int qt = sub & 15;
  const int b = hb / H_;
  const int h = hb - b * H_;
  const int rowbase = b * N_;
  const int qcol = h * DH_;
  const int kcol = DIM_ + qcol;

  // Q fragment (B-operand: col=q15, k=d=g*8+j+32ks), pre-scaled by SCL_
  bf16x8 qf[2];
  {
    const int qrow = rowbase + (qt << 6) + (w << 4) + q15;
    const u16* src = qkv + (size_t)qrow * NQKV_ + qcol + (g << 3);
#pragma unroll
    for (int ks = 0; ks < 2; ++ks) {
      u16x8 raw = *(const u16x8*)(src + ks * 32);
      bf16x8 o;
#pragma unroll
      for (int j = 0; j < 8; ++j) o[j] = (short)f2bf(bf2f(raw[j]) * SCL_);
      qf[ks] = o;
    }
  }

  float mrow = -1e30f, lrow = 0.f;
  f32x4 oacc[4];
#pragma unroll
  for (int d = 0; d < 4; ++d) oacc[d] = (f32x4){0.f, 0.f, 0.f, 0.f};

  // staging: thread t owns LDS bytes t*16 (rows 0..31) and (t+256)*16
  // (rows 32..63); source chunk pre-swizzled: c' = c ^ (row&7)  (rule #21).
  const int sr = t >> 3;
  const int c8 = t & 7;
  const int loff0 = t << 4, loff1 = (t + 256) << 4;
  const u16* pk0 = qkv + (size_t)(rowbase + sr) * NQKV_ + kcol + ((c8 ^ (sr & 7)) << 3);
  const u16* pk1 = qkv + (size_t)(rowbase + sr + 32) * NQKV_ + kcol + ((c8 ^ (sr & 7)) << 3);
  const u16* pv0 = vT + (((size_t)(hb * 64 + sr)) << 10) + ((c8 ^ (sr & 7)) << 3);
  const u16* pv1 = vT + (((size_t)(hb * 64 + sr + 32)) << 10) + ((c8 ^ (sr & 7)) << 3);
  char* lk0 = (char*)Ks;   // buffer stride 8192 B
  char* lv0 = (char*)Vt;
  char* lp = (char*)Ps + (w << 11);

#define ASTAGE(BUFO)                                       \
  do {                                                     \
    async16(pk0, lk0 + (BUFO) + loff0);                    \
    async16(pk1, lk0 + (BUFO) + loff1);                    \
    async16(pv0, lv0 + (BUFO) + loff0);                    \
    async16(pv1, lv0 + (BUFO) + loff1);                    \
    pk0 += (size_t)64 * NQKV_; pk1 += (size_t)64 * NQKV_;  \
    pv0 += 64; pv1 += 64;                                  \
  } while (0)

  // loop-invariant read offsets (note: kv&7 == d&7 == q15&7 across uses)
  const int rowB = q15 << 7;
  const int xsw = (q15 & 7) << 4;
  const int x0 = (g << 4) ^ xsw;
  const int x1 = (64 + (g << 4)) ^ xsw;

  ASTAGE(0);  // tile 0 -> buf0
  VMCNT0_BARRIER();
  for (int kvt = 0; kvt < 16; kvt += 2) {
    // phase 0: compute buf0 (tile kvt), prefetch tile kvt+1 -> buf1
    ASTAGE(8192);
    attn_tile<0, 0>(lk0, lv0, lp, qf, oacc, mrow, lrow, rowB, xsw, x0, x1, g);
    VMCNT0_BARRIER();
    // phase 1: compute buf1 (tile kvt+1), prefetch tile kvt+2 -> buf0
    if (kvt < 14) ASTAGE(0);
    attn_tile<8192, 8192>(lk0, lv0, lp, qf, oacc, mrow, lrow, rowB, xsw, x0, x1, g);
    VMCNT0_BARRIER();
  }
#undef ASTAGE

  // epilogue: normalize, write o[token][h*64+d] (bf16)
  float rl = 1.f / lrow;
  float rlj[4];
#pragma unroll
  for (int j = 0; j < 4; ++j) rlj[j] = __shfl(rl, (g << 2) + j, 64);
  const int orow0 = rowbase + (qt << 6) + (w << 4) + (g << 2);
#pragma unroll
  for (int dt = 0; dt < 4; ++dt) {
    int col = qcol + (dt << 4) + q15;
#pragma unroll
    for (int j = 0; j < 4; ++j)
      ob[(size_t)(orow0 + j) * DIM_ + col] = f2bf(oacc[dt][j] * rlj[j]);
  }
}

// ---------------- launch ----------------
extern "C" void kernel_launch(void* const* d_in, const int* in_sizes, int n_in,
                              void* d_out, int out_size, void* d_ws, size_t ws_size,
                              hipStream_t stream) {
  const float* x = (const float*)d_in[0];
  const float* w_qkv = (const float*)d_in[1];
  const float* w_out = (const float*)d_in[2];
  const float* b_out = (const float*)d_in[3];

  u16* xb = (u16*)d_ws;                               // 8192*768
  u16* wqkvb = xb + (size_t)M_ * DIM_;                // 2304*768
  u16* woutb = wqkvb + (size_t)NQKV_ * DIM_;          // 768*768
  u16* qkvb = woutb + (size_t)DIM_ * DIM_;            // 8192*2304 (V third unused)
  u16* obuf = qkvb + (size_t)M_ * NQKV_;              // 8192*768
  u16* vT = obuf + (size_t)M_ * DIM_;                 // 96*64*1024 transposed V
  // total ~80.2 MB of workspace

  {
    int n4 = M_ * DIM_ / 4;
    cast_bf16_k<<<(n4 + 255) / 256, 256, 0, stream>>>(x, xb, n4);
  }
  {
    int n4 = NQKV_ * DIM_ / 4;
    cast_bf16_k<<<(n4 + 255) / 256, 256, 0, stream>>>(w_qkv, wqkvb, n4);
  }
  {
    int n4 = DIM_ * DIM_ / 4;
    cast_bf16_k<<<(n4 + 255) / 256, 256, 0, stream>>>(w_out, woutb, n4);
  }

  gemm_bt_k<true, false, true><<<dim3(NQKV_ / 128, M_ / 128), 256, 0, stream>>>(
      xb, wqkvb, (void*)qkvb, nullptr, DIM_, NQKV_, vT);

  attn_k<<<dim3(B_ * H_ * 16), 256, 0, stream>>>(qkvb, vT, obuf);

  gemm_bt_k<false, true, false><<<dim3(DIM_ / 128, M_ / 128), 256, 0, stream>>>(
      obuf, woutb, d_out, b_out, DIM_, DIM_, nullptr);
}